// Round 14
// baseline (106.694 us; speedup 1.0000x reference)
//
#include <hip/hip_runtime.h>
#include <hip/hip_bf16.h>
#include <stdint.h>

typedef unsigned short ushort_t;
typedef _Float16 h16x8 __attribute__((ext_vector_type(8)));   // 8 f16 in 4 VGPRs
typedef _Float16 h16x2 __attribute__((ext_vector_type(2)));
typedef __attribute__((ext_vector_type(4))) float f32x4;

#define BB 4
#define SS 2048
#define HDIM 1024
#define NH 16
#define DF 64
#define WWIN 16

// ---- merged QKV GEMM: C[8192,3072] = X[8192,1024] @ W[3072,1024]^T ----
#define GM 8192
#define GN 3072
#define GK 1024
#define BM 256
#define BN 256
#define BK 64
#define NITER 8                 // 16 K-tiles, 2 per iteration
#define ABYTES 32768            // A region per buffer (256x64 f16)
#define BUFB 65536              // A + B per buffer
#define LDS_TOT 131072

#if defined(__has_builtin)
#if __has_builtin(__builtin_amdgcn_fdot2)
#define HAS_FDOT2 1
#endif
#endif

__device__ __forceinline__ ushort_t f2h(float f) {
    union { _Float16 h; ushort_t u; } c;
    c.h = (_Float16)f;
    return c.u;
}
__device__ __forceinline__ float h2f(ushort_t u) {
    union { ushort_t u; _Float16 h; } c;
    c.u = u;
    return (float)c.h;
}
__device__ __forceinline__ float fdot2acc(h16x2 a, h16x2 b, float c) {
#ifdef HAS_FDOT2
    return __builtin_amdgcn_fdot2(a, b, c, false);
#else
    return c + (float)a[0] * (float)b[0] + (float)a[1] * (float)b[1];
#endif
}

__device__ __forceinline__ void gld_lds16(const void* g, void* l) {
    __builtin_amdgcn_global_load_lds(
        (const __attribute__((address_space(1))) void*)g,
        (__attribute__((address_space(3))) void*)l, 16, 0, 0);
}

// ------------- fused fp32 -> f16 convert (x + Wq + Wk + Wv + pad rows) -----
__global__ void cvt_all(const float* __restrict__ x,
                        const float* __restrict__ Wq, const float* __restrict__ Wk,
                        const float* __restrict__ Wv,
                        const float* __restrict__ bk, const float* __restrict__ bv,
                        ushort_t* __restrict__ xb, ushort_t* __restrict__ Wb,
                        ushort_t* __restrict__ kpadF, ushort_t* __restrict__ vpadF) {
    const int NX = 2097152, NW = 262144;
    int i = blockIdx.x * blockDim.x + threadIdx.x;
    int st = gridDim.x * blockDim.x;
    for (; i < NX + 3 * NW; i += st) {
        const float* src; ushort_t* dst; int j;
        if (i < NX) { src = x; dst = xb; j = i; }
        else {
            int k = i - NX; int w = k >> 18; j = k & (NW - 1);
            src = (w == 0) ? Wq : ((w == 1) ? Wk : Wv);
            dst = Wb + (size_t)w * NW * 4;
        }
        float4 v = ((const float4*)src)[j];
        ushort4 o;
        o.x = f2h(v.x); o.y = f2h(v.y); o.z = f2h(v.z); o.w = f2h(v.w);
        ((ushort4*)dst)[j] = o;
    }
    if (blockIdx.x == 0) {
#pragma unroll
        for (int it = 0; it < 4; ++it) {
            int idx = it * 256 + threadIdx.x;
            if (idx < 1024) {
                kpadF[idx] = f2h(bk[idx]);
                vpadF[idx] = f2h(bv[idx]);
            }
        }
    }
}

// ---------------- QKV GEMM: faithful 8-phase / 2-K-tile pipeline -----------
// 256x256, BK=64, 8 waves (2M x 4N, 128x64/wave). Even tiles in buf0, odd in
// buf1. Per phase: {ds_reads (12/4/8/0, fragment-reuse) | stage 1 half-tile
// (2 gld_lds)} -> s_barrier -> lgkmcnt(0)+sched_barrier -> setprio(1) 16 MFMA
// setprio(0) -> s_barrier. vmcnt(6) ONLY at P4/P8 (ledger-proven: confirms
// exactly the tile the next 4 phases read; 3-7-phase stage->confirm lead).
// Stage cadence P1:To.A1 | P2:Te'.A0 P3:Te'.B0 P4:Te'.B1 P5:Te'.A1 |
// P6:To'.A0 P7:To'.B0 P8:To'.B1. Write-after-read safe via phase barriers.
__global__ __launch_bounds__(512, 2) void gemm_qkv8(
    const ushort_t* __restrict__ Aall,   // [8192][1024] f16
    const ushort_t* __restrict__ Wall,   // [3072][1024] f16 (Wq|Wk|Wv)
    const float* __restrict__ bq, const float* __restrict__ bk, const float* __restrict__ bv,
    ushort_t* __restrict__ Obase)        // [3][8192][1024] f16
{
    extern __shared__ char lds[];
    const int t = threadIdx.x;
    const int wave = t >> 6, lane = t & 63;
    const int wm = wave >> 2, wn = wave & 3;     // 2M x 4N -> 128x64 per wave
    const int frow = lane & 15, g = lane >> 4;
    const int sw = frow & 7;
    const int rr = t >> 3;

    // XCD-bijective decode: 384 blocks = 8 chunks of 48
    const int bid = blockIdx.x;
    const int wgid = (bid & 7) * 48 + (bid >> 3);
    const int bx = wgid / 12;                    // 0..31 (M tile)
    const int by = wgid % 12;                    // 0..11 (N tile)
    const int m0 = bx * BM;
    const int nG0 = by * BN;

    char* const b0 = lds;
    char* const b1 = lds + BUFB;

    // A-group ga (16KB): local row lr=r*64+rr <-> global m0 + r*128 + ga*64 + rr
    auto STAGE_A = [&](char* Nb, int kt, int ga) {
#pragma unroll
        for (int r = 0; r < 2; ++r) {
            const int lr = r * 64 + rr;
            const int grow = m0 + r * 128 + ga * 64 + rr;
            const int gcol = kt * BK + (((t & 7) ^ (lr & 7)) << 3);
            gld_lds16(Aall + (size_t)grow * GK + gcol,
                      Nb + ga * 16384 + r * 8192 + wave * 1024);
        }
    };
    // B-group gb (16KB): local row lr <-> global nG0 + (lr>>5)*64 + gb*32 + (lr&31)
    auto STAGE_B = [&](char* Nb, int kt, int gb) {
#pragma unroll
        for (int r = 0; r < 2; ++r) {
            const int lr = r * 64 + rr;
            const int grow = nG0 + (lr >> 5) * 64 + gb * 32 + (lr & 31);
            const int gcol = kt * BK + (((t & 7) ^ (lr & 7)) << 3);
            gld_lds16(Wall + (size_t)grow * GK + gcol,
                      Nb + ABYTES + gb * 16384 + r * 8192 + wave * 1024);
        }
    };

    f32x4 acc[2][2][4][2] = {};
    h16x8 afr[4][2];           // current qm-group A fragments
    h16x8 bfr[2][2][2];        // [qn][nj][kk] — both B groups held across a tile

#define LOAD_A(BUF, qm_) \
    _Pragma("unroll") \
    for (int mi = 0; mi < 4; ++mi) \
    _Pragma("unroll") \
    for (int kk = 0; kk < 2; ++kk) \
        afr[mi][kk] = *(const h16x8*)((BUF) + (qm_) * 16384 \
            + ((wm * 64 + mi * 16 + frow) << 7) \
            + ((((kk << 2) + g) ^ sw) << 4));

#define LOAD_B(BUF, qn_) \
    _Pragma("unroll") \
    for (int nj = 0; nj < 2; ++nj) \
    _Pragma("unroll") \
    for (int kk = 0; kk < 2; ++kk) \
        bfr[qn_][nj][kk] = *(const h16x8*)((BUF) + ABYTES + (qn_) * 16384 \
            + ((wn * 32 + nj * 16 + frow) << 7) \
            + ((((kk << 2) + g) ^ sw) << 4));

#define MFMA_Q(qm_, qn_) \
    _Pragma("unroll") \
    for (int mi = 0; mi < 4; ++mi) \
    _Pragma("unroll") \
    for (int nj = 0; nj < 2; ++nj) \
    _Pragma("unroll") \
    for (int kk = 0; kk < 2; ++kk) \
        acc[qm_][qn_][mi][nj] = __builtin_amdgcn_mfma_f32_16x16x32_f16( \
            bfr[qn_][nj][kk], afr[mi][kk], acc[qm_][qn_][mi][nj], 0, 0, 0);

#define PH(QM_, QN_) \
    asm volatile("s_barrier" ::: "memory"); \
    asm volatile("s_waitcnt lgkmcnt(0)" ::: "memory"); \
    __builtin_amdgcn_sched_barrier(0); \
    __builtin_amdgcn_s_setprio(1); \
    MFMA_Q(QM_, QN_) \
    __builtin_amdgcn_s_setprio(0); \
    asm volatile("s_barrier" ::: "memory");

    // prologue: T0 fully (A0,B0,B1,A1) + T1's A0,B0,B1 (A1 deferred to P1)
    STAGE_A(b0, 0, 0); STAGE_B(b0, 0, 0); STAGE_B(b0, 0, 1); STAGE_A(b0, 0, 1);
    STAGE_A(b1, 1, 0); STAGE_B(b1, 1, 0); STAGE_B(b1, 1, 1);
    asm volatile("s_waitcnt vmcnt(6)\ns_barrier" ::: "memory");   // T0 landed

#pragma unroll 1
    for (int it = 0; it < NITER; ++it) {
        const int te = 2 * it + 2;       // next even tile
        const int to = 2 * it + 3;       // next odd tile
        const bool st = (it + 1 < NITER);

        // ---- even tile (buf0) ----
        // P1: reads A0+B0 (12), stage current-odd A1 (deferred slot)
        LOAD_A(b0, 0)
        LOAD_B(b0, 0)
        STAGE_A(b1, 2 * it + 1, 1);
        PH(0, 0)

        // P2: reads B1 (4), stage Te'.A0
        LOAD_B(b0, 1)
        if (st) STAGE_A(b0, te, 0);
        PH(0, 1)

        // P3: reads A1 (8), stage Te'.B0
        LOAD_A(b0, 1)
        if (st) STAGE_B(b0, te, 0);
        PH(1, 1)

        // P4: no reads, stage Te'.B1, counted wait -> current odd tile landed
        if (st) {
            STAGE_B(b0, te, 1);
            asm volatile("s_waitcnt vmcnt(6)" ::: "memory");
        } else {
            asm volatile("s_waitcnt vmcnt(0)" ::: "memory");
        }
        PH(1, 0)

        // ---- odd tile (buf1) ----
        // P5: reads A0+B0 (12), stage Te'.A1
        LOAD_A(b1, 0)
        LOAD_B(b1, 0)
        if (st) STAGE_A(b0, te, 1);
        PH(0, 0)

        // P6: reads B1 (4), stage To'.A0
        LOAD_B(b1, 1)
        if (st) STAGE_A(b1, to, 0);
        PH(0, 1)

        // P7: reads A1 (8), stage To'.B0
        LOAD_A(b1, 1)
        if (st) STAGE_B(b1, to, 0);
        PH(1, 1)

        // P8: no reads, stage To'.B1, counted wait -> Te' landed
        if (st) STAGE_B(b1, to, 1);
        asm volatile("s_waitcnt vmcnt(6)" ::: "memory");   // no-op on last iter
        PH(1, 0)
    }

    // ---- epilogue: lane holds 4 consecutive cols at fixed row (frow) ----
#pragma unroll
    for (int qm = 0; qm < 2; ++qm)
#pragma unroll
    for (int qn = 0; qn < 2; ++qn)
#pragma unroll
    for (int nj = 0; nj < 2; ++nj) {
        const int colb = nG0 + wn * 64 + qn * 32 + nj * 16;   // 16-aligned: single z
        const int z = colb >> 10;
        const int nin = (colb & 1023) + g * 4;
        const float* bias = (z == 0) ? bq : ((z == 1) ? bk : bv);
        ushort_t* OutZ = Obase + (size_t)z * GM * 1024;
        float4 b4 = *(const float4*)(bias + nin);
#pragma unroll
        for (int mi = 0; mi < 4; ++mi) {
            const size_t rowoff = (size_t)(m0 + wm * 128 + qm * 64 + mi * 16 + frow) * 1024;
            ushort4 o;
            o.x = f2h(acc[qm][qn][mi][nj][0] + b4.x);
            o.y = f2h(acc[qm][qn][mi][nj][1] + b4.y);
            o.z = f2h(acc[qm][qn][mi][nj][2] + b4.z);
            o.w = f2h(acc[qm][qn][mi][nj][3] + b4.w);
            *(ushort4*)(OutZ + rowoff + nin) = o;
        }
    }
#undef LOAD_A
#undef LOAD_B
#undef MFMA_Q
#undef PH
}

// ---------------- attention: anti-diagonal r-groups (frozen, R9) -----------
__global__ __launch_bounds__(256) void attn_kernel(
    const ushort_t* __restrict__ Qb, const ushort_t* __restrict__ Kb,
    const ushort_t* __restrict__ Vb, const ushort_t* __restrict__ kpadF,
    const ushort_t* __restrict__ vpadF, float* __restrict__ out)
{
    __shared__ float aS[4][4][16];
    const int wave = threadIdx.x >> 6, lane = threadIdx.x & 63;
    const int r = (int)blockIdx.x - (WWIN - 1);         // -15..2047
    const int bS = blockIdx.y * SS;
    const bool pad = (r < 0);
    const int rc = pad ? 0 : r;
    const ushort_t* krow = pad ? kpadF : Kb + ((size_t)(bS + rc) << 10);
    const ushort_t* vrow = pad ? vpadF : Vb + ((size_t)(bS + rc) << 10);

    h16x8 k0 = *(const h16x8*)(krow + (lane << 4));
    h16x8 k1 = *(const h16x8*)(krow + (lane << 4) + 8);
    const h16x2* ka = (const h16x2*)&k0;
    const h16x2* kc = (const h16x2*)&k1;

    float vv[16];
#pragma unroll
    for (int w = 0; w < 16; ++w) vv[w] = h2f(vrow[(w << 6) + lane]);

    const int dq = (lane & 3) << 4;
    bool val[4];
    size_t qb[4];

#pragma unroll
    for (int qi = 0; qi < 4; ++qi) {
        const int h = (wave << 2) + qi;
        const int s = r + (WWIN - 1) - h;
        const bool v = ((unsigned)s) < SS;
        const int sc = v ? s : 0;
        const size_t qbase = ((size_t)(bS + sc) << 10) + (h << 6);
        val[qi] = v; qb[qi] = qbase;

        h16x8 q0 = *(const h16x8*)(Qb + qbase + dq);
        h16x8 q1 = *(const h16x8*)(Qb + qbase + dq + 8);
        const h16x2* qa = (const h16x2*)&q0;
        const h16x2* qc = (const h16x2*)&q1;
        float p = 0.f;
#pragma unroll
        for (int j = 0; j < 4; ++j) {
            p = fdot2acc(qa[j], ka[j], p);
            p = fdot2acc(qc[j], kc[j], p);
        }
        p *= 0.125f;
        p += __shfl_xor(p, 1);
        p += __shfl_xor(p, 2);

        float e = __expf(p);
        float sm = e;
#pragma unroll
        for (int d = 4; d < 64; d <<= 1) sm += __shfl_xor(sm, d);
        if ((lane & 3) == 0) aS[wave][qi][lane >> 2] = e / sm;
    }
    asm volatile("s_waitcnt lgkmcnt(0)" ::: "memory");

#pragma unroll
    for (int qi = 0; qi < 4; ++qi) {
        const float4 a0 = *(const float4*)&aS[wave][qi][0];
        const float4 a1 = *(const float4*)&aS[wave][qi][4];
        const float4 a2 = *(const float4*)&aS[wave][qi][8];
        const float4 a3 = *(const float4*)&aS[wave][qi][12];
        float s0 = a0.x * vv[0] + a0.y * vv[1] + a0.z * vv[2] + a0.w * vv[3];
        float s1 = a1.x * vv[4] + a1.y * vv[5] + a1.z * vv[6] + a1.w * vv[7];
        float s2 = a2.x * vv[8] + a2.y * vv[9] + a2.z * vv[10] + a2.w * vv[11];
        float s3 = a3.x * vv[12] + a3.y * vv[13] + a3.z * vv[14] + a3.w * vv[15];
        if (val[qi]) out[qb[qi] + lane] = (s0 + s1) + (s2 + s3);
    }
}

extern "C" void kernel_launch(void* const* d_in, const int* in_sizes, int n_in,
                              void* d_out, int out_size, void* d_ws, size_t ws_size,
                              hipStream_t stream) {
    const float* x  = (const float*)d_in[0];
    const float* Wq = (const float*)d_in[1];
    const float* bq = (const float*)d_in[2];
    const float* Wk = (const float*)d_in[3];
    const float* bk = (const float*)d_in[4];
    const float* Wv = (const float*)d_in[5];
    const float* bv = (const float*)d_in[6];
    float* out = (float*)d_out;

    ushort_t* xb    = (ushort_t*)d_ws;                     // 8192*1024 f16
    ushort_t* Wb    = xb + (size_t)8192 * 1024;            // 3 * 1024*1024 f16
    ushort_t* QKV   = Wb + (size_t)3 * 1024 * 1024;        // 3 * 8192*1024 f16
    ushort_t* Qb    = QKV;
    ushort_t* Kb    = QKV + (size_t)8192 * 1024;
    ushort_t* Vb    = QKV + (size_t)2 * 8192 * 1024;
    ushort_t* kpadF = QKV + (size_t)3 * 8192 * 1024;       // 1024 f16
    ushort_t* vpadF = kpadF + 1024;                        // 1024 f16

    cvt_all<<<2048, 256, 0, stream>>>(x, Wq, Wk, Wv, bk, bv, xb, Wb, kpadF, vpadF);

    hipFuncSetAttribute(reinterpret_cast<const void*>(gemm_qkv8),
                        hipFuncAttributeMaxDynamicSharedMemorySize, LDS_TOT);
    gemm_qkv8<<<dim3((GM / BM) * (GN / BN)), 512, LDS_TOT, stream>>>(
        xb, Wb, bq, bk, bv, QKV);

    attn_kernel<<<dim3(SS + WWIN - 1, BB), 256, 0, stream>>>(
        Qb, Kb, Vb, kpadF, vpadF, out);
}

// Round 15
// 91.412 us; speedup vs baseline: 1.1672x; 1.1672x over previous
//
#include <hip/hip_runtime.h>
#include <hip/hip_bf16.h>
#include <stdint.h>

typedef unsigned short ushort_t;
typedef _Float16 h16x8 __attribute__((ext_vector_type(8)));   // 8 f16 in 4 VGPRs
typedef _Float16 h16x2 __attribute__((ext_vector_type(2)));
typedef __attribute__((ext_vector_type(4))) float f32x4;

#define BB 4
#define SS 2048
#define HDIM 1024
#define NH 16
#define DF 64
#define WWIN 16

// ---- merged QKV GEMM: C[8192,3072] = X[8192,1024] @ W[3072,1024]^T ----
#define GM 8192
#define GN 3072
#define GK 1024
#define BM 256
#define BN 192
#define BK 64
#define NT (GK / BK)                          // 16 K-tiles
#define ABYTES (BM * BK * 2)                  // 32768
#define LDS_TILE (BM * BK * 2 + BN * BK * 2)  // 57344 B per buffer
#define NBUF 2

#if defined(__has_builtin)
#if __has_builtin(__builtin_amdgcn_fdot2)
#define HAS_FDOT2 1
#endif
#endif

__device__ __forceinline__ ushort_t f2h(float f) {
    union { _Float16 h; ushort_t u; } c;
    c.h = (_Float16)f;
    return c.u;
}
__device__ __forceinline__ float h2f(ushort_t u) {
    union { ushort_t u; _Float16 h; } c;
    c.u = u;
    return (float)c.h;
}
__device__ __forceinline__ float fdot2acc(h16x2 a, h16x2 b, float c) {
#ifdef HAS_FDOT2
    return __builtin_amdgcn_fdot2(a, b, c, false);
#else
    return c + (float)a[0] * (float)b[0] + (float)a[1] * (float)b[1];
#endif
}

__device__ __forceinline__ void gld_lds16(const void* g, void* l) {
    __builtin_amdgcn_global_load_lds(
        (const __attribute__((address_space(1))) void*)g,
        (__attribute__((address_space(3))) void*)l, 16, 0, 0);
}

// ------------- fused fp32 -> f16 convert (x + Wq + Wk + Wv + pad rows) -----
__global__ void cvt_all(const float* __restrict__ x,
                        const float* __restrict__ Wq, const float* __restrict__ Wk,
                        const float* __restrict__ Wv,
                        const float* __restrict__ bk, const float* __restrict__ bv,
                        ushort_t* __restrict__ xb, ushort_t* __restrict__ Wb,
                        ushort_t* __restrict__ kpadF, ushort_t* __restrict__ vpadF) {
    const int NX = 2097152, NW = 262144;
    int i = blockIdx.x * blockDim.x + threadIdx.x;
    int st = gridDim.x * blockDim.x;
    for (; i < NX + 3 * NW; i += st) {
        const float* src; ushort_t* dst; int j;
        if (i < NX) { src = x; dst = xb; j = i; }
        else {
            int k = i - NX; int w = k >> 18; j = k & (NW - 1);
            src = (w == 0) ? Wq : ((w == 1) ? Wk : Wv);
            dst = Wb + (size_t)w * NW * 4;
        }
        float4 v = ((const float4*)src)[j];
        ushort4 o;
        o.x = f2h(v.x); o.y = f2h(v.y); o.z = f2h(v.z); o.w = f2h(v.w);
        ((ushort4*)dst)[j] = o;
    }
    if (blockIdx.x == 0) {
#pragma unroll
        for (int it = 0; it < 4; ++it) {
            int idx = it * 256 + threadIdx.x;
            if (idx < 1024) {
                kpadF[idx] = f2h(bk[idx]);
                vpadF[idx] = f2h(bv[idx]);
            }
        }
    }
}

// ---------------- QKV GEMM: 256x192 tile, per-wave 128x48 (frozen R4/f16) --
// 8 waves (2M x 4N), BK=64, double-buffered LDS, issue-early staging,
// chunk^(row&7) swizzle (0 conflicts), operand-swapped MFMA epilogue,
// bijective XCD chunking. Structure ceiling ~830 TF verified over 5 variants.
__global__ __launch_bounds__(512, 2) void gemm_qkv8(
    const ushort_t* __restrict__ Aall,   // [8192][1024] f16
    const ushort_t* __restrict__ Wall,   // [3072][1024] f16 (Wq|Wk|Wv)
    const float* __restrict__ bq, const float* __restrict__ bk, const float* __restrict__ bv,
    ushort_t* __restrict__ Obase)        // [3][8192][1024] f16
{
    extern __shared__ char lds[];
    const int t = threadIdx.x;
    const int wave = t >> 6, lane = t & 63;
    const int wm = wave >> 2, wn = wave & 3;     // 2M x 4N wave grid -> 128x48 per wave
    const int frow = lane & 15, g = lane >> 4;
    const int sw = frow & 7;

    const int bid = blockIdx.x;
    const int cc = bid & 7, w = bid >> 3;
    const int bx = (cc & 3) * 8 + (w & 7);       // 0..31  (M tile)
    const int by = (cc >> 2) * 8 + (w >> 3);     // 0..15  (N tile)
    const int m0 = bx * BM;
    const int nG0 = by * BN;

    auto STAGE = [&](int bufb, int kt) {
        const int kc = kt * BK;
        char* Lb = lds + bufb;
#pragma unroll
        for (int r = 0; r < 4; ++r) {
            int idx = r * 512 + t;
            int row = idx >> 3, slot = idx & 7;
            gld_lds16(Aall + (size_t)(m0 + row) * GK + kc + ((slot ^ (row & 7)) << 3),
                      Lb + ((r * 512 + wave * 64) << 4));
        }
#pragma unroll
        for (int r = 0; r < 3; ++r) {
            int idx = r * 512 + t;
            int row = idx >> 3, slot = idx & 7;
            gld_lds16(Wall + (size_t)(nG0 + row) * GK + kc + ((slot ^ (row & 7)) << 3),
                      Lb + ABYTES + ((r * 512 + wave * 64) << 4));
        }
    };

    f32x4 acc[8][3] = {};

    STAGE(0, 0);
    asm volatile("s_waitcnt vmcnt(0)\ns_barrier" ::: "memory");

#pragma unroll 2
    for (int tt = 0; tt < NT; ++tt) {
        if (tt + 1 < NT) STAGE(((tt + 1) & 1) * LDS_TILE, tt + 1);

        const char* Ab = lds + (tt & 1) * LDS_TILE;
        const char* Bb = Ab + ABYTES;

#pragma unroll
        for (int kk = 0; kk < 2; ++kk) {
            h16x8 af[8], bf[3];
#pragma unroll
            for (int i = 0; i < 8; ++i)
                af[i] = *(const h16x8*)(Ab + ((wm * 128 + i * 16 + frow) << 7)
                                           + ((((kk << 2) + g) ^ sw) << 4));
#pragma unroll
            for (int j = 0; j < 3; ++j)
                bf[j] = *(const h16x8*)(Bb + ((wn * 48 + j * 16 + frow) << 7)
                                           + ((((kk << 2) + g) ^ sw) << 4));
            __builtin_amdgcn_s_setprio(1);
#pragma unroll
            for (int i = 0; i < 8; ++i)
#pragma unroll
                for (int j = 0; j < 3; ++j)
                    acc[i][j] = __builtin_amdgcn_mfma_f32_16x16x32_f16(bf[j], af[i], acc[i][j], 0, 0, 0);
            __builtin_amdgcn_s_setprio(0);
        }

        if (tt + 1 < NT)
            asm volatile("s_waitcnt vmcnt(0)\ns_barrier" ::: "memory");
    }

    const int m_base = m0 + wm * 128;
#pragma unroll
    for (int j = 0; j < 3; ++j) {
        const int colb = nG0 + wn * 48 + j * 16;
        const int z = colb >> 10;
        const int nin = (colb & 1023) + g * 4;
        const float* bias = (z == 0) ? bq : ((z == 1) ? bk : bv);
        ushort_t* OutZ = Obase + (size_t)z * GM * 1024;
        float4 b4 = *(const float4*)(bias + nin);
#pragma unroll
        for (int i = 0; i < 8; ++i) {
            const size_t rowoff = (size_t)(m_base + i * 16 + frow) * 1024;
            ushort4 o;
            o.x = f2h(acc[i][j][0] + b4.x);
            o.y = f2h(acc[i][j][1] + b4.y);
            o.z = f2h(acc[i][j][2] + b4.z);
            o.w = f2h(acc[i][j][3] + b4.w);
            *(ushort4*)(OutZ + rowoff + nin) = o;
        }
    }
}

// ---------------- attention: anti-diagonal r-groups (frozen, R9) -----------
// Block = (b, r): the 16 queries (s,h) with s+h-15 == r all read K/V row r.
// 4 waves x 4 queries; K in regs + V converted once per wave, shared by 4
// queries. Each K/V row read by exactly ONE block -> single-pass HBM.
__global__ __launch_bounds__(256) void attn_kernel(
    const ushort_t* __restrict__ Qb, const ushort_t* __restrict__ Kb,
    const ushort_t* __restrict__ Vb, const ushort_t* __restrict__ kpadF,
    const ushort_t* __restrict__ vpadF, float* __restrict__ out)
{
    __shared__ float aS[4][4][16];
    const int wave = threadIdx.x >> 6, lane = threadIdx.x & 63;
    const int r = (int)blockIdx.x - (WWIN - 1);         // -15..2047
    const int bS = blockIdx.y * SS;
    const bool pad = (r < 0);
    const int rc = pad ? 0 : r;
    const ushort_t* krow = pad ? kpadF : Kb + ((size_t)(bS + rc) << 10);
    const ushort_t* vrow = pad ? vpadF : Vb + ((size_t)(bS + rc) << 10);

    h16x8 k0 = *(const h16x8*)(krow + (lane << 4));
    h16x8 k1 = *(const h16x8*)(krow + (lane << 4) + 8);
    const h16x2* ka = (const h16x2*)&k0;
    const h16x2* kc = (const h16x2*)&k1;

    float vv[16];
#pragma unroll
    for (int w = 0; w < 16; ++w) vv[w] = h2f(vrow[(w << 6) + lane]);

    const int dq = (lane & 3) << 4;
    bool val[4];
    size_t qb[4];

#pragma unroll
    for (int qi = 0; qi < 4; ++qi) {
        const int h = (wave << 2) + qi;
        const int s = r + (WWIN - 1) - h;
        const bool v = ((unsigned)s) < SS;
        const int sc = v ? s : 0;
        const size_t qbase = ((size_t)(bS + sc) << 10) + (h << 6);
        val[qi] = v; qb[qi] = qbase;

        h16x8 q0 = *(const h16x8*)(Qb + qbase + dq);
        h16x8 q1 = *(const h16x8*)(Qb + qbase + dq + 8);
        const h16x2* qa = (const h16x2*)&q0;
        const h16x2* qc = (const h16x2*)&q1;
        float p = 0.f;
#pragma unroll
        for (int j = 0; j < 4; ++j) {
            p = fdot2acc(qa[j], ka[j], p);
            p = fdot2acc(qc[j], kc[j], p);
        }
        p *= 0.125f;
        p += __shfl_xor(p, 1);
        p += __shfl_xor(p, 2);

        float e = __expf(p);
        float sm = e;
#pragma unroll
        for (int d = 4; d < 64; d <<= 1) sm += __shfl_xor(sm, d);
        if ((lane & 3) == 0) aS[wave][qi][lane >> 2] = e / sm;
    }
    asm volatile("s_waitcnt lgkmcnt(0)" ::: "memory");

#pragma unroll
    for (int qi = 0; qi < 4; ++qi) {
        const float4 a0 = *(const float4*)&aS[wave][qi][0];
        const float4 a1 = *(const float4*)&aS[wave][qi][4];
        const float4 a2 = *(const float4*)&aS[wave][qi][8];
        const float4 a3 = *(const float4*)&aS[wave][qi][12];
        float s0 = a0.x * vv[0] + a0.y * vv[1] + a0.z * vv[2] + a0.w * vv[3];
        float s1 = a1.x * vv[4] + a1.y * vv[5] + a1.z * vv[6] + a1.w * vv[7];
        float s2 = a2.x * vv[8] + a2.y * vv[9] + a2.z * vv[10] + a2.w * vv[11];
        float s3 = a3.x * vv[12] + a3.y * vv[13] + a3.z * vv[14] + a3.w * vv[15];
        if (val[qi]) out[qb[qi] + lane] = (s0 + s1) + (s2 + s3);
    }
}

extern "C" void kernel_launch(void* const* d_in, const int* in_sizes, int n_in,
                              void* d_out, int out_size, void* d_ws, size_t ws_size,
                              hipStream_t stream) {
    const float* x  = (const float*)d_in[0];
    const float* Wq = (const float*)d_in[1];
    const float* bq = (const float*)d_in[2];
    const float* Wk = (const float*)d_in[3];
    const float* bk = (const float*)d_in[4];
    const float* Wv = (const float*)d_in[5];
    const float* bv = (const float*)d_in[6];
    float* out = (float*)d_out;

    ushort_t* xb    = (ushort_t*)d_ws;                     // 8192*1024 f16
    ushort_t* Wb    = xb + (size_t)8192 * 1024;            // 3 * 1024*1024 f16
    ushort_t* QKV   = Wb + (size_t)3 * 1024 * 1024;        // 3 * 8192*1024 f16
    ushort_t* Qb    = QKV;
    ushort_t* Kb    = QKV + (size_t)8192 * 1024;
    ushort_t* Vb    = QKV + (size_t)2 * 8192 * 1024;
    ushort_t* kpadF = QKV + (size_t)3 * 8192 * 1024;       // 1024 f16
    ushort_t* vpadF = kpadF + 1024;                        // 1024 f16

    cvt_all<<<2048, 256, 0, stream>>>(x, Wq, Wk, Wv, bk, bv, xb, Wb, kpadF, vpadF);

    hipFuncSetAttribute(reinterpret_cast<const void*>(gemm_qkv8),
                        hipFuncAttributeMaxDynamicSharedMemorySize, NBUF * LDS_TILE);
    gemm_qkv8<<<dim3((GM / BM) * (GN / BN)), 512, NBUF * LDS_TILE, stream>>>(
        xb, Wb, bq, bk, bv, QKV);

    attn_kernel<<<dim3(SS + WWIN - 1, BB), 256, 0, stream>>>(
        Qb, Kb, Vb, kpadF, vpadF, out);
}